// Round 2
// baseline (1451.842 us; speedup 1.0000x reference)
//
#include <hip/hip_runtime.h>

#define D 128

typedef __attribute__((ext_vector_type(8))) short bf16x8;
typedef __attribute__((ext_vector_type(4))) float f32x4;

__device__ __forceinline__ unsigned short f2bf(float f) {
    unsigned int u = __builtin_bit_cast(unsigned int, f);
    u = (u + 0x7fffu + ((u >> 16) & 1u)) >> 16;
    return (unsigned short)u;
}

__global__ void zero_kernel(float* __restrict__ p, int n4) {
    int i = blockIdx.x * 256 + threadIdx.x;
    if (i < n4) ((float4*)p)[i] = make_float4(0.f, 0.f, 0.f, 0.f);
}

// One wave (64 lanes) per edge; lane i handles features [2i, 2i+1].
__global__ void scatter_kernel(const float* __restrict__ x,
                               const int* __restrict__ esrc,
                               const int* __restrict__ edst,
                               const float* __restrict__ eval,
                               float* __restrict__ support, int E) {
    int e = blockIdx.x * 4 + (threadIdx.x >> 6);
    if (e >= E) return;
    int lane = threadIdx.x & 63;
    int src = esrc[e];
    int dst = edst[e];
    float val = eval[e];
    float2 v = *(const float2*)(x + (size_t)src * D + lane * 2);
    float* sp = support + (size_t)dst * D + lane * 2;
    unsafeAtomicAdd(sp,     v.x * val);
    unsafeAtomicAdd(sp + 1, v.y * val);
}

// Block = 256 threads (4 waves) handles 64 rows x 128 cols of out.
// h = [x_row | support_row] cast to bf16, staged in LDS (row padded to 264
// shorts to break bank aliasing). Each wave owns 32 output cols; its W
// fragments (2 col-tiles x 8 k-steps, bf16) live in 64 VGPRs.
__global__ __launch_bounds__(256) void gemm_kernel(
        const float* __restrict__ x,
        const float* __restrict__ support,
        const float* __restrict__ W,
        const float* __restrict__ bias,
        float* __restrict__ out, int N) {
    __shared__ unsigned short hA[64 * 264];
    const int tid = threadIdx.x;
    const int row0 = blockIdx.x * 64;

    // Stage x tile: 64 rows x 128 fp32 -> bf16. float4 per task -> 2048 tasks.
    for (int t = tid; t < 2048; t += 256) {
        int r = t >> 5, c = (t & 31) << 2;
        int rg = row0 + r;
        float4 v = make_float4(0.f, 0.f, 0.f, 0.f);
        if (rg < N) v = *(const float4*)(x + (size_t)rg * D + c);
        ushort4 s;
        s.x = f2bf(v.x); s.y = f2bf(v.y); s.z = f2bf(v.z); s.w = f2bf(v.w);
        *(ushort4*)(hA + r * 264 + c) = s;
    }
    // Stage support tile: same shape, offset +128 in the padded row.
    for (int t = tid; t < 2048; t += 256) {
        int r = t >> 5, c = (t & 31) << 2;
        int rg = row0 + r;
        float4 v = make_float4(0.f, 0.f, 0.f, 0.f);
        if (rg < N) v = *(const float4*)(support + (size_t)rg * D + c);
        ushort4 s;
        s.x = f2bf(v.x); s.y = f2bf(v.y); s.z = f2bf(v.z); s.w = f2bf(v.w);
        *(ushort4*)(hA + r * 264 + 128 + c) = s;
    }

    const int lane = tid & 63;
    const int quad = lane >> 4;
    const int l15  = lane & 15;
    const int colbase = (tid >> 6) * 32;  // wave id * 32 cols

    // Preload W fragments: B[k = ks*32 + quad*8 + j][n = colbase + ct*16 + l15]
    bf16x8 wfrag[2][8];
#pragma unroll
    for (int ct = 0; ct < 2; ++ct) {
        int col = colbase + ct * 16 + l15;
#pragma unroll
        for (int ks = 0; ks < 8; ++ks) {
            bf16x8 f;
#pragma unroll
            for (int j = 0; j < 8; ++j)
                f[j] = (short)f2bf(W[(size_t)(ks * 32 + quad * 8 + j) * D + col]);
            wfrag[ct][ks] = f;
        }
    }

    __syncthreads();

    f32x4 acc[4][2];
#pragma unroll
    for (int rt = 0; rt < 4; ++rt)
#pragma unroll
        for (int ct = 0; ct < 2; ++ct)
            acc[rt][ct] = (f32x4){0.f, 0.f, 0.f, 0.f};

#pragma unroll
    for (int ks = 0; ks < 8; ++ks) {
#pragma unroll
        for (int rt = 0; rt < 4; ++rt) {
            // A[m = rt*16 + l15][k = ks*32 + quad*8 + j] -- 16B contiguous
            bf16x8 a = *(const bf16x8*)(hA + (rt * 16 + l15) * 264 + ks * 32 + quad * 8);
#pragma unroll
            for (int ct = 0; ct < 2; ++ct)
                acc[rt][ct] = __builtin_amdgcn_mfma_f32_16x16x32_bf16(
                    a, wfrag[ct][ks], acc[rt][ct], 0, 0, 0);
        }
    }

    // Epilogue: D[row = quad*4 + reg][col = l15] per 16x16 tile, + bias, fp32 out
#pragma unroll
    for (int ct = 0; ct < 2; ++ct) {
        int col = colbase + ct * 16 + l15;
        float bv = bias[col];
#pragma unroll
        for (int rt = 0; rt < 4; ++rt) {
#pragma unroll
            for (int rg = 0; rg < 4; ++rg) {
                int row = row0 + rt * 16 + quad * 4 + rg;
                if (row < N)
                    out[(size_t)row * D + col] = acc[rt][ct][rg] + bv;
            }
        }
    }
}

extern "C" void kernel_launch(void* const* d_in, const int* in_sizes, int n_in,
                              void* d_out, int out_size, void* d_ws, size_t ws_size,
                              hipStream_t stream) {
    const float* x    = (const float*)d_in[0];
    const int*   esrc = (const int*)d_in[1];
    const int*   edst = (const int*)d_in[2];
    const float* eval = (const float*)d_in[3];
    const float* W    = (const float*)d_in[4];
    const float* bias = (const float*)d_in[5];
    float*       out  = (float*)d_out;

    const int N = in_sizes[0] / D;   // 100000
    const int E = in_sizes[1];       // 1600000
    float* support = (float*)d_ws;   // N*D fp32 accumulator = 51.2 MB

    const int n4 = (N * D) / 4;
    zero_kernel<<<(n4 + 255) / 256, 256, 0, stream>>>(support, n4);
    scatter_kernel<<<(E + 3) / 4, 256, 0, stream>>>(x, esrc, edst, eval, support, E);
    gemm_kernel<<<(N + 63) / 64, 256, 0, stream>>>(x, support, W, bias, out, N);
}

// Round 3
// 461.047 us; speedup vs baseline: 3.1490x; 3.1490x over previous
//
#include <hip/hip_runtime.h>

#define D 128

typedef __attribute__((ext_vector_type(8))) short bf16x8;
typedef __attribute__((ext_vector_type(4))) float f32x4;

__device__ __forceinline__ unsigned short f2bf(float f) {
    unsigned int u = __builtin_bit_cast(unsigned int, f);
    u = (u + 0x7fffu + ((u >> 16) & 1u)) >> 16;
    return (unsigned short)u;
}

__global__ void zero_int_kernel(int* __restrict__ p, int n) {
    int i = blockIdx.x * 256 + threadIdx.x;
    if (i < n) p[i] = 0;
}

// WT_bf[col*256 + k] = bf16(W[k*128 + col]);  W is [256,128] fp32.
__global__ void wprep_kernel(const float* __restrict__ W,
                             unsigned short* __restrict__ WT) {
    int t = blockIdx.x * 256 + threadIdx.x;   // 32768 total
    int col = t & 127, k = t >> 7;
    WT[col * 256 + k] = f2bf(W[k * D + col]);
}

__global__ void hist_kernel(const int* __restrict__ edst,
                            int* __restrict__ deg, int E) {
    int e = blockIdx.x * 256 + threadIdx.x;
    if (e < E) atomicAdd(&deg[edst[e]], 1);
}

// Allocate a contiguous slice per node: wave-aggregated bump allocation.
__global__ void alloc_kernel(const int* __restrict__ deg,
                             int* __restrict__ counter,
                             int* __restrict__ offsets,
                             int* __restrict__ cursor, int N) {
    int n = blockIdx.x * 256 + threadIdx.x;
    int lane = threadIdx.x & 63;
    int d = (n < N) ? deg[n] : 0;
    // inclusive prefix sum across the wave
    int v = d;
#pragma unroll
    for (int off = 1; off < 64; off <<= 1) {
        int t = __shfl_up(v, off, 64);
        if (lane >= off) v += t;
    }
    int wavesum = __shfl(v, 63, 64);
    int base = 0;
    if (lane == 63) base = atomicAdd(counter, wavesum);
    base = __shfl(base, 63, 64);
    if (n < N) {
        int start = base + v - d;   // exclusive
        offsets[n] = start;
        cursor[n] = start;
    }
}

__global__ void fill_kernel(const int* __restrict__ esrc,
                            const int* __restrict__ edst,
                            const float* __restrict__ eval,
                            int* __restrict__ cursor,
                            int2* __restrict__ edge_pack, int E) {
    int e = blockIdx.x * 256 + threadIdx.x;
    if (e >= E) return;
    int dst = edst[e];
    int p = atomicAdd(&cursor[dst], 1);
    edge_pack[p] = make_int2(esrc[e], __builtin_bit_cast(int, eval[e]));
}

// One wave per node: accumulate its neighborhood in registers (float2/lane),
// write support row once as bf16.
__global__ void gather_kernel(const float* __restrict__ x,
                              const int* __restrict__ offsets,
                              const int* __restrict__ deg,
                              const int2* __restrict__ edge_pack,
                              unsigned short* __restrict__ support_bf, int N) {
    int n = blockIdx.x * 4 + (threadIdx.x >> 6);
    if (n >= N) return;
    int lane = threadIdx.x & 63;
    int start = offsets[n];
    int dg = deg[n];
    float ax = 0.f, ay = 0.f;
    int j = 0;
    for (; j + 2 <= dg; j += 2) {
        int2 e0 = edge_pack[start + j];
        int2 e1 = edge_pack[start + j + 1];
        float2 v0 = *(const float2*)(x + (size_t)e0.x * D + lane * 2);
        float2 v1 = *(const float2*)(x + (size_t)e1.x * D + lane * 2);
        float val0 = __builtin_bit_cast(float, e0.y);
        float val1 = __builtin_bit_cast(float, e1.y);
        ax += v0.x * val0; ay += v0.y * val0;
        ax += v1.x * val1; ay += v1.y * val1;
    }
    if (j < dg) {
        int2 e0 = edge_pack[start + j];
        float2 v0 = *(const float2*)(x + (size_t)e0.x * D + lane * 2);
        float val0 = __builtin_bit_cast(float, e0.y);
        ax += v0.x * val0; ay += v0.y * val0;
    }
    ushort2 s;
    s.x = f2bf(ax); s.y = f2bf(ay);
    *(ushort2*)(support_bf + (size_t)n * D + lane * 2) = s;
}

// Block = 256 threads (4 waves) -> 64 rows x 128 cols of out.
// h = [x_row (fp32->bf16) | support_row (bf16)] staged in LDS, row padded to
// 264 shorts. Each wave owns 32 cols; W fragments via 16B loads from WT_bf.
__global__ __launch_bounds__(256) void gemm_kernel(
        const float* __restrict__ x,
        const unsigned short* __restrict__ support_bf,
        const unsigned short* __restrict__ WT,
        const float* __restrict__ bias,
        float* __restrict__ out, int N) {
    __shared__ unsigned short hA[64 * 264];
    const int tid = threadIdx.x;
    const int row0 = blockIdx.x * 64;

    // Stage x tile: 64 rows x 128 fp32 -> bf16. float4 per task -> 2048 tasks.
    for (int t = tid; t < 2048; t += 256) {
        int r = t >> 5, c = (t & 31) << 2;
        int rg = row0 + r;
        float4 v = make_float4(0.f, 0.f, 0.f, 0.f);
        if (rg < N) v = *(const float4*)(x + (size_t)rg * D + c);
        ushort4 s;
        s.x = f2bf(v.x); s.y = f2bf(v.y); s.z = f2bf(v.z); s.w = f2bf(v.w);
        *(ushort4*)(hA + r * 264 + c) = s;
    }
    // Stage support tile (already bf16): uint4 per task -> 1024 tasks.
    for (int t = tid; t < 1024; t += 256) {
        int r = t >> 4, c = (t & 15) << 3;
        int rg = row0 + r;
        uint4 v = make_uint4(0u, 0u, 0u, 0u);
        if (rg < N) v = *(const uint4*)(support_bf + (size_t)rg * D + c);
        *(uint4*)(hA + r * 264 + 128 + c) = v;
    }

    const int lane = tid & 63;
    const int quad = lane >> 4;
    const int l15  = lane & 15;
    const int colbase = (tid >> 6) * 32;  // wave id * 32 cols

    // W fragments: B[k = ks*32 + quad*8 + j][col] = WT[col*256 + k] (16B loads)
    bf16x8 wfrag[2][8];
#pragma unroll
    for (int ct = 0; ct < 2; ++ct) {
        int col = colbase + ct * 16 + l15;
#pragma unroll
        for (int ks = 0; ks < 8; ++ks)
            wfrag[ct][ks] = *(const bf16x8*)(WT + (size_t)col * 256 + ks * 32 + quad * 8);
    }

    __syncthreads();

    f32x4 acc[4][2];
#pragma unroll
    for (int rt = 0; rt < 4; ++rt)
#pragma unroll
        for (int ct = 0; ct < 2; ++ct)
            acc[rt][ct] = (f32x4){0.f, 0.f, 0.f, 0.f};

#pragma unroll
    for (int ks = 0; ks < 8; ++ks) {
#pragma unroll
        for (int rt = 0; rt < 4; ++rt) {
            bf16x8 a = *(const bf16x8*)(hA + (rt * 16 + l15) * 264 + ks * 32 + quad * 8);
#pragma unroll
            for (int ct = 0; ct < 2; ++ct)
                acc[rt][ct] = __builtin_amdgcn_mfma_f32_16x16x32_bf16(
                    a, wfrag[ct][ks], acc[rt][ct], 0, 0, 0);
        }
    }

    // Epilogue: D[row = quad*4 + reg][col = l15] per 16x16 tile, + bias.
#pragma unroll
    for (int ct = 0; ct < 2; ++ct) {
        int col = colbase + ct * 16 + l15;
        float bv = bias[col];
#pragma unroll
        for (int rt = 0; rt < 4; ++rt) {
#pragma unroll
            for (int rg = 0; rg < 4; ++rg) {
                int row = row0 + rt * 16 + quad * 4 + rg;
                if (row < N)
                    out[(size_t)row * D + col] = acc[rt][ct][rg] + bv;
            }
        }
    }
}

extern "C" void kernel_launch(void* const* d_in, const int* in_sizes, int n_in,
                              void* d_out, int out_size, void* d_ws, size_t ws_size,
                              hipStream_t stream) {
    const float* x    = (const float*)d_in[0];
    const int*   esrc = (const int*)d_in[1];
    const int*   edst = (const int*)d_in[2];
    const float* eval = (const float*)d_in[3];
    const float* W    = (const float*)d_in[4];
    const float* bias = (const float*)d_in[5];
    float*       out  = (float*)d_out;

    const int N = in_sizes[0] / D;   // 100000
    const int E = in_sizes[1];       // 1600000

    // ws layout (bytes):
    char* ws = (char*)d_ws;
    unsigned short* support_bf = (unsigned short*)ws;              // N*D*2 = 25,600,000
    int2*           edge_pack  = (int2*)(ws + 25600000);           // E*8   = 12,800,000
    unsigned short* WT         = (unsigned short*)(ws + 38400000); // 65,536
    int*            deg        = (int*)(ws + 38465536);            // N*4   = 400,000
    int*            counter    = (int*)(ws + 38865536);            // 4 (contiguous after deg)
    int*            offsets    = (int*)(ws + 38865552);            // 400,000
    int*            cursor     = (int*)(ws + 39265552);            // 400,000

    zero_int_kernel<<<(N + 1 + 255) / 256, 256, 0, stream>>>(deg, N + 1); // deg + counter
    wprep_kernel<<<(2 * D * D) / 256, 256, 0, stream>>>(W, WT);
    hist_kernel<<<(E + 255) / 256, 256, 0, stream>>>(edst, deg, E);
    alloc_kernel<<<(N + 255) / 256, 256, 0, stream>>>(deg, counter, offsets, cursor, N);
    fill_kernel<<<(E + 255) / 256, 256, 0, stream>>>(esrc, edst, eval, cursor, edge_pack, E);
    gather_kernel<<<(N + 3) / 4, 256, 0, stream>>>(x, offsets, deg, edge_pack, support_bf, N);
    gemm_kernel<<<(N + 63) / 64, 256, 0, stream>>>(x, support_bf, WT, bias, out, N);
}